// Round 21
// baseline (600.244 us; speedup 1.0000x reference)
//
#include <hip/hip_runtime.h>

typedef _Float16 f16;
typedef unsigned short u16;
typedef unsigned int u32;
typedef long long i64;
typedef __attribute__((ext_vector_type(8))) _Float16 f16x8;
typedef __attribute__((ext_vector_type(4))) float f32x4;

#define IN_F 4096
#define OUT_F 4096

__device__ __forceinline__ void gload16(const f16* g, f16* l) {
  __builtin_amdgcn_global_load_lds(
      (const __attribute__((address_space(1))) void*)g,
      (__attribute__((address_space(3))) void*)l, 16, 0, 0);
}

// ---------------------------------------------------------------------------
// prep kernels
// ---------------------------------------------------------------------------
__global__ __launch_bounds__(256) void cvt_f32_f16(
    const float* __restrict__ in, f16* __restrict__ out, i64 n8) {
  i64 s = (i64)gridDim.x * blockDim.x;
  for (i64 j = (i64)blockIdx.x * blockDim.x + threadIdx.x; j < n8; j += s) {
    float4 a = ((const float4*)in)[2 * j];
    float4 b = ((const float4*)in)[2 * j + 1];
    f16x8 o;
    o[0] = (f16)a.x; o[1] = (f16)a.y; o[2] = (f16)a.z; o[3] = (f16)a.w;
    o[4] = (f16)b.x; o[5] = (f16)b.y; o[6] = (f16)b.z; o[7] = (f16)b.w;
    ((f16x8*)out)[j] = o;
  }
}

__global__ __launch_bounds__(256) void zero32(u32* __restrict__ p, i64 n) {
  i64 s = (i64)gridDim.x * blockDim.x;
  for (i64 j = (i64)blockIdx.x * blockDim.x + threadIdx.x; j < n; j += s) p[j] = 0u;
}

__global__ __launch_bounds__(256) void scatter_woh(
    const float* __restrict__ vals, const int* __restrict__ rows,
    const int* __restrict__ cols, f16* __restrict__ woh, int nnz) {
  int i = blockIdx.x * blockDim.x + threadIdx.x;
  if (i >= nnz) return;
  int r = rows[i], c = cols[i];
  if (r < 0 || r >= OUT_F || c < 0 || c >= IN_F) return;
  float v = vals[i];
  size_t idx = (size_t)r * IN_F + c;
  u32* p = (u32*)woh + (idx >> 1);
  u32 sh = (u32)(idx & 1) * 16u;
  union { f16 h; u16 u; } cv;
  u32 old = *p;
  while (true) {
    u32 assumed = old;
    cv.u = (u16)((assumed >> sh) & 0xFFFFu);
    float cur = (float)cv.h;
    cv.h = (f16)(cur + v);
    u32 nw = (assumed & ~(0xFFFFu << sh)) | ((u32)cv.u << sh);
    old = atomicCAS(p, assumed, nw);
    if (old == assumed) break;
  }
}

// ---------------------------------------------------------------------------
// 256x256 GEMM, m201-style quadrant schedule (R21), 16x16x32 MFMA:
//  ph1: read af_h0(8)+bf_n0(4) -> Q(h0,n0); ph2: read bf_n1(4) -> Q(h0,n1);
//  ph3: read af_h1(8) -> Q(h1,n1); ph4: re-read bf_n0(4) -> Q(h1,n0).
//  Stage order A0,A2 / B0,B1 / B2,B3 / A1,A3; gates vmcnt(4) at ph1/ph2/ph4
//  (FIFO-audited, every stage >=3 phases cover).  B rows remapped in LDS:
//  u -> rB(u)=((u>>5)&3)*64+((u>>7)&1)*32+(u&31) so n-halves = chunk pairs
//  (u&7==r&7 keeps the XOR swizzle involution on both sides).
//  T2 swizzle, XCD 8x8 panels, T5 setprio.
//  STREAM 0: out = f32(f16(acc));  1: out += acc.
// ---------------------------------------------------------------------------
template <int STREAM>
__global__ __launch_bounds__(512, 2) void gemm_256(
    const f16* __restrict__ Xh, const f16* __restrict__ Bm,
    float* __restrict__ out, int M) {
  __shared__ alignas(16) f16 As[2][16384];
  __shared__ alignas(16) f16 Bs[2][16384];

  const int tid = threadIdx.x;
  const int lane = tid & 63;
  const int wave = tid >> 6;
  const int wr = wave >> 2;         // 0..1  (M half)
  const int wc = wave & 3;          // 0..3  (N quarter)
  const int lo = lane & 15, hi = lane >> 4, l7 = lane & 7;

  const int bid = (int)blockIdx.x;
  const int nbn = OUT_F / 256;                      // 16
  const int nbm = M / 256;
  int browi, bcoli;
  if (nbm == 32 && nbn == 16) {
    const int xcd = bid & 7;
    const int j   = bid >> 3;                       // 0..63
    const int jr  = j >> 3, jc = j & 7;
    browi = (xcd & 3) * 8 + jr;                     // [0,32)
    bcoli = (xcd >> 2) * 8 + jc;                    // [0,16)
  } else {
    const int nwg = nbm * nbn;
    const int swz = ((nwg & 7) == 0) ? ((bid & 7) * (nwg >> 3) + (bid >> 3)) : bid;
    browi = swz / nbn;
    bcoli = swz % nbn;
  }
  const int brow = browi << 8;
  const int bcol = bcoli << 8;

  // staging chunks: c = i*512+tid; LDS dest = c*8 (lane-linear);
  // A: row u = c>>3 (identity).  B: row rB(u) (n-half remap).
  // kchunk = (c&7)^(u&7)  [T2 pre-swizzle; u&7 == row&7 in both maps]
  int aglob[4], bglob[4], ldst[4];
#pragma unroll
  for (int i = 0; i < 4; ++i) {
    int c = i * 512 + tid;
    int u = c >> 3;
    int kc = (c & 7) ^ (u & 7);
    ldst[i] = c * 8;
    aglob[i] = (brow + u) * IN_F + kc * 8;
    int rB = (((u >> 5) & 3) << 6) + (((u >> 7) & 1) << 5) + (u & 31);
    bglob[i] = (bcol + rB) * IN_F + kc * 8;
  }

  // fragment read offsets (16x16): slot[ks] = (((ks<<2)|hi) ^ l7)*8
  // af(h,mf,ks):  abase + h*4096 + mf*1024 + slot[ks]
  // bf(nt,nf,ks): bbase + nt*8192 + nf*1024 + slot[ks]   [u-space rows]
  const int abase = (wr * 128 + lo) * 64;
  const int bbase = (wc * 32 + lo) * 64;
  const int slot0 = (hi ^ l7) * 8;
  const int slot1 = ((4 + hi) ^ l7) * 8;

  f32x4 acc[8][4] = {};

  // prologue: stage tile 0 -> buf 0: A0,A2,B0,B1,B2,B3,A1,A3
  gload16(Xh + aglob[0], &As[0][ldst[0]]);
  gload16(Xh + aglob[2], &As[0][ldst[2]]);
  gload16(Bm + bglob[0], &Bs[0][ldst[0]]);
  gload16(Bm + bglob[1], &Bs[0][ldst[1]]);
  gload16(Bm + bglob[2], &Bs[0][ldst[2]]);
  gload16(Bm + bglob[3], &Bs[0][ldst[3]]);
  gload16(Xh + aglob[1], &As[0][ldst[1]]);
  gload16(Xh + aglob[3], &As[0][ldst[3]]);
  asm volatile("s_waitcnt vmcnt(4)" ::: "memory");  // A0,A2,B0,B1 landed
  __builtin_amdgcn_sched_barrier(0);
  __builtin_amdgcn_s_barrier();

  // 16-MFMA quadrant cluster (ks outer: same-acc dep distance 8)
#define CLUSTER(BF, MO, NO)                                                    \
  __builtin_amdgcn_s_setprio(1);                                               \
  _Pragma("unroll")                                                            \
  for (int ks = 0; ks < 2; ++ks)                                               \
    _Pragma("unroll")                                                          \
    for (int mf = 0; mf < 4; ++mf)                                             \
      _Pragma("unroll")                                                        \
      for (int nf = 0; nf < 2; ++nf)                                           \
        acc[(MO) + mf][(NO) + nf] = __builtin_amdgcn_mfma_f32_16x16x32_f16(    \
            af[mf][ks], BF[nf][ks], acc[(MO) + mf][(NO) + nf], 0, 0, 0);       \
  __builtin_amdgcn_s_setprio(0);

  const int NT = IN_F / 64;                 // 64
  for (int kt = 0; kt < NT; ++kt) {
    const f16* A = &As[kt & 1][0];
    const f16* B = &Bs[kt & 1][0];
    f16* An = &As[(kt & 1) ^ 1][0];
    f16* Bn = &Bs[(kt & 1) ^ 1][0];
    const int kn = (kt + 1) * 64;
    const bool pf = (kt + 1 < NT);

    f16x8 af[4][2], bf0[2][2], bf1[2][2];

    // ---- ph1: read af_h0 (8) + bf_n0 (4) | stage A0',A2' | gate B2,B3
#pragma unroll
    for (int mf = 0; mf < 4; ++mf) {
      af[mf][0] = *(const f16x8*)(A + abase + mf * 1024 + slot0);
      af[mf][1] = *(const f16x8*)(A + abase + mf * 1024 + slot1);
    }
#pragma unroll
    for (int nf = 0; nf < 2; ++nf) {
      bf0[nf][0] = *(const f16x8*)(B + bbase + nf * 1024 + slot0);
      bf0[nf][1] = *(const f16x8*)(B + bbase + nf * 1024 + slot1);
    }
    if (pf) { gload16(Xh + aglob[0] + kn, An + ldst[0]);
              gload16(Xh + aglob[2] + kn, An + ldst[2]); }
    if (pf) asm volatile("s_waitcnt vmcnt(4)" ::: "memory");
    else    asm volatile("s_waitcnt vmcnt(2)" ::: "memory");
    __builtin_amdgcn_sched_barrier(0);
    __builtin_amdgcn_s_barrier();
    CLUSTER(bf0, 0, 0)
    __builtin_amdgcn_s_barrier();

    // ---- ph2: read bf_n1 (4) | stage B0',B1' | gate A1,A3
#pragma unroll
    for (int nf = 0; nf < 2; ++nf) {
      bf1[nf][0] = *(const f16x8*)(B + bbase + 8192 + nf * 1024 + slot0);
      bf1[nf][1] = *(const f16x8*)(B + bbase + 8192 + nf * 1024 + slot1);
    }
    if (pf) { gload16(Bm + bglob[0] + kn, Bn + ldst[0]);
              gload16(Bm + bglob[1] + kn, Bn + ldst[1]); }
    if (pf) asm volatile("s_waitcnt vmcnt(4)" ::: "memory");
    else    asm volatile("s_waitcnt vmcnt(0)" ::: "memory");
    __builtin_amdgcn_sched_barrier(0);
    __builtin_amdgcn_s_barrier();
    CLUSTER(bf1, 0, 2)
    __builtin_amdgcn_s_barrier();

    // ---- ph3: read af_h1 (8) | stage B2',B3' | no gate
#pragma unroll
    for (int mf = 0; mf < 4; ++mf) {
      af[mf][0] = *(const f16x8*)(A + abase + 4096 + mf * 1024 + slot0);
      af[mf][1] = *(const f16x8*)(A + abase + 4096 + mf * 1024 + slot1);
    }
    if (pf) { gload16(Bm + bglob[2] + kn, Bn + ldst[2]);
              gload16(Bm + bglob[3] + kn, Bn + ldst[3]); }
    __builtin_amdgcn_s_barrier();
    CLUSTER(bf1, 4, 2)
    __builtin_amdgcn_s_barrier();

    // ---- ph4: re-read bf_n0 (4) | stage A1',A3' | gate A0',A2',B0',B1'
#pragma unroll
    for (int nf = 0; nf < 2; ++nf) {
      bf0[nf][0] = *(const f16x8*)(B + bbase + nf * 1024 + slot0);
      bf0[nf][1] = *(const f16x8*)(B + bbase + nf * 1024 + slot1);
    }
    if (pf) { gload16(Xh + aglob[1] + kn, An + ldst[1]);
              gload16(Xh + aglob[3] + kn, An + ldst[3]); }
    if (pf) {
      asm volatile("s_waitcnt vmcnt(4)" ::: "memory");
      __builtin_amdgcn_sched_barrier(0);
    }
    __builtin_amdgcn_s_barrier();
    CLUSTER(bf0, 4, 0)
    __builtin_amdgcn_s_barrier();
  }
#undef CLUSTER

  // epilogue.  C/D: col = lane&15, row = (lane>>4)*4 + r  (m89-verified)
  const int crow0 = brow + wr * 128 + (hi << 2);
  const int ccol0 = bcol + wc * 64 + lo;
#pragma unroll
  for (int mf = 0; mf < 8; ++mf)
#pragma unroll
    for (int nf = 0; nf < 4; ++nf)
#pragma unroll
      for (int r = 0; r < 4; ++r) {
        float* p = out + (size_t)(crow0 + mf * 16 + r) * OUT_F + (ccol0 + nf * 16);
        if constexpr (STREAM == 0)
          *p = (float)(f16)acc[mf][nf][r];
        else
          *p += acc[mf][nf][r];
      }
}

// ---------------------------------------------------------------------------
// R12 fallback (proven): 128x128, 2-barrier, reg-staged A from f32
// ---------------------------------------------------------------------------
template <bool A16, int STREAM>
__global__ __launch_bounds__(256, 2) void gemm_one(
    const float* __restrict__ Xf, const f16* __restrict__ Xh,
    const f16* __restrict__ Bm, float* __restrict__ out, int M) {
  constexpr int LDA = A16 ? 32 : 40;
  __shared__ alignas(16) f16 As[128 * LDA];
  __shared__ alignas(16) f16 Bs[128 * 32];

  const int tid = threadIdx.x, lane = tid & 63, wave = tid >> 6;
  const int wr = wave >> 1, wc = wave & 1;
  const int nbn = OUT_F / 128;
  const int nwg = (int)gridDim.x;
  const int bid = (int)blockIdx.x;
  const int swz = ((nwg & 7) == 0) ? ((bid & 7) * (nwg >> 3) + (bid >> 3)) : bid;
  const int brow = (swz / nbn) << 7;
  const int bcol = (swz % nbn) << 7;

  f32x4 acc[4][4] = {};
  const int srow = tid >> 2, sk = (tid & 3) * 8;
  const f16* gB = Bm + (size_t)(bcol + srow) * IN_F + sk;
  f16* sB = Bs + tid * 8;
  const f16*   gA = A16 ? (Xh + (size_t)(brow + srow) * IN_F + sk) : (const f16*)nullptr;
  const float* gX = A16 ? (const float*)nullptr : (Xf + (size_t)(brow + srow) * IN_F + sk);
  f16* sA  = As + tid * 8;
  f16* sAr = As + srow * LDA + sk;
  const f16* pa = As + (wr * 64 + (lane & 15)) * LDA + (lane >> 4) * 8;
  const f16* pb = Bs + (wc * 64 + (lane & 15)) * 32 + (lane >> 4) * 8;

  for (int k0 = 0; k0 < IN_F; k0 += 32) {
    if constexpr (A16) {
      gload16(gA + k0, sA);
      gload16(gA + k0 + (size_t)64 * IN_F, sA + 2048);
    } else {
      float4 u0 = *(const float4*)(gX + k0);
      float4 u1 = *(const float4*)(gX + k0 + 4);
      float4 v0 = *(const float4*)(gX + k0 + (size_t)64 * IN_F);
      float4 v1 = *(const float4*)(gX + k0 + (size_t)64 * IN_F + 4);
      f16x8 h0, h1;
      h0[0] = (f16)u0.x; h0[1] = (f16)u0.y; h0[2] = (f16)u0.z; h0[3] = (f16)u0.w;
      h0[4] = (f16)u1.x; h0[5] = (f16)u1.y; h0[6] = (f16)u1.z; h0[7] = (f16)u1.w;
      h1[0] = (f16)v0.x; h1[1] = (f16)v0.y; h1[2] = (f16)v0.z; h1[3] = (f16)v0.w;
      h1[4] = (f16)v1.x; h1[5] = (f16)v1.y; h1[6] = (f16)v1.z; h1[7] = (f16)v1.w;
      *(f16x8*)sAr = h0;
      *(f16x8*)(sAr + 64 * LDA) = h1;
    }
    gload16(gB + k0, sB);
    gload16(gB + k0 + (size_t)64 * IN_F, sB + 2048);
    __syncthreads();
    f16x8 af[4], bfr[4];
#pragma unroll
    for (int m = 0; m < 4; ++m) af[m] = *(const f16x8*)(pa + m * 16 * LDA);
#pragma unroll
    for (int n = 0; n < 4; ++n) bfr[n] = *(const f16x8*)(pb + n * 512);
#pragma unroll
    for (int m = 0; m < 4; ++m)
#pragma unroll
      for (int n = 0; n < 4; ++n)
        acc[m][n] = __builtin_amdgcn_mfma_f32_16x16x32_f16(af[m], bfr[n], acc[m][n], 0, 0, 0);
    __syncthreads();
  }
  const int crow0 = brow + wr * 64 + ((lane >> 4) << 2);
  const int ccol0 = bcol + wc * 64 + (lane & 15);
#pragma unroll
  for (int m = 0; m < 4; ++m)
#pragma unroll
    for (int n = 0; n < 4; ++n)
#pragma unroll
      for (int r = 0; r < 4; ++r) {
        float* p = out + (size_t)(crow0 + m * 16 + r) * OUT_F + (ccol0 + n * 16);
        if constexpr (STREAM == 0) *p = (float)(f16)acc[m][n][r];
        else *p += acc[m][n][r];
      }
}

// ---------------------------------------------------------------------------
extern "C" void kernel_launch(void* const* d_in, const int* in_sizes, int n_in,
                              void* d_out, int out_size, void* d_ws, size_t ws_size,
                              hipStream_t stream) {
  const float* x    = (const float*)d_in[0];
  const float* W    = (const float*)d_in[1];
  const float* vals = (const float*)d_in[2];
  const int*   rows = (const int*)d_in[3];
  const int*   cols = (const int*)d_in[4];
  float*       out  = (float*)d_out;

  const i64 total_x = (i64)in_sizes[0];
  const int M   = (int)(total_x / IN_F);            // 8192
  const int nnz = in_sizes[2];
  if (M <= 0 || M % 128 != 0) return;

  const size_t whb = (size_t)OUT_F * IN_F * 2;      // 32 MB
  const size_t xhb = (size_t)M * IN_F * 2;          // 64 MB

  if (ws_size >= xhb + 2 * whb) {
    f16* xh  = (f16*)d_ws;
    f16* wh  = (f16*)((char*)d_ws + xhb);
    f16* woh = (f16*)((char*)d_ws + xhb + whb);
    cvt_f32_f16<<<2048, 256, 0, stream>>>(x, xh, total_x / 8);
    cvt_f32_f16<<<2048, 256, 0, stream>>>(W, wh, (i64)OUT_F * IN_F / 8);
    zero32<<<2048, 256, 0, stream>>>((u32*)woh, (i64)(whb / 4));
    scatter_woh<<<(nnz + 255) / 256, 256, 0, stream>>>(vals, rows, cols, woh, nnz);
    if (M % 256 == 0) {
      const int grid = (M / 256) * (OUT_F / 256);   // 512
      gemm_256<0><<<grid, 512, 0, stream>>>(xh, wh, out, M);
      gemm_256<1><<<grid, 512, 0, stream>>>(xh, woh, out, M);
    } else {
      const int grid = (M / 128) * (OUT_F / 128);
      gemm_one<true, 0><<<grid, 256, 0, stream>>>(nullptr, xh, wh, out, M);
      gemm_one<true, 1><<<grid, 256, 0, stream>>>(nullptr, xh, woh, out, M);
    }
  } else if (ws_size >= 2 * whb) {
    f16* wh  = (f16*)d_ws;
    f16* woh = (f16*)((char*)d_ws + whb);
    cvt_f32_f16<<<2048, 256, 0, stream>>>(W, wh, (i64)OUT_F * IN_F / 8);
    zero32<<<2048, 256, 0, stream>>>((u32*)woh, (i64)(whb / 4));
    scatter_woh<<<(nnz + 255) / 256, 256, 0, stream>>>(vals, rows, cols, woh, nnz);
    const int grid = (M / 128) * (OUT_F / 128);
    gemm_one<false, 0><<<grid, 256, 0, stream>>>(x, nullptr, wh, out, M);
    gemm_one<false, 1><<<grid, 256, 0, stream>>>(x, nullptr, woh, out, M);
  }
}